// Round 9
// baseline (1119.248 us; speedup 1.0000x reference)
//
#include <hip/hip_runtime.h>
#include <hip/hip_bf16.h>

// Single-CU-autonomous LSTM: 128 blocks x 512 threads, BC=16 batches/block.
// Full W_hh (1024x256 bf16 = 512 KB) per block: 6/8 tiles per wave in the
// unified VGPR/AGPR file (384 KB), 2/8 tiles in LDS (128 KB). No cross-block
// communication. x*w_x + bias folded as MFMA acc-INIT (C=0) with A-frags
// hoisted to registers; K-loop loads batched 12-deep for latency hiding.

#define TT 256
#define HH 256
#define BC 16
#define NTH 512

typedef __attribute__((ext_vector_type(8))) short short8;
typedef __attribute__((ext_vector_type(4))) float floatx4;

__device__ __forceinline__ unsigned short f2bf(float f) {
    union { float f; unsigned u; } v; v.f = f;
    unsigned r = v.u + 0x7FFFu + ((v.u >> 16) & 1u);   // RNE, finite inputs only
    return (unsigned short)(r >> 16);
}
__device__ __forceinline__ float sigf(float x) {
    return __builtin_amdgcn_rcpf(1.f + __expf(-x));
}
__device__ __forceinline__ float tanh_(float x) {
    return 1.f - 2.f * __builtin_amdgcn_rcpf(__expf(2.f * x) + 1.f);
}

__global__ __attribute__((amdgpu_flat_work_group_size(512, 512),
                          amdgpu_waves_per_eu(2, 2)))
void lstm_onecu(
    const float* __restrict__ y_hist, const float* __restrict__ h0,
    const float* __restrict__ c0, const float* __restrict__ W_ih,
    const float* __restrict__ W_hh, const float* __restrict__ b_ih,
    const float* __restrict__ b_hh, const float* __restrict__ W_fc,
    const float* __restrict__ b_fc, float* __restrict__ out)
{
    // LDS budget (160 KB): W tiles 128K + h ping-pong 16K + x 8K
    __shared__ __align__(16) char  WLDS[131072];   // [w][ti][s][lane] 16B frags
    __shared__ __align__(16) char  hb[2][8192];    // [b 16][hid 256] bf16, swz
    __shared__ unsigned short xw[TT * BC];         // bf16(x) [t][b]
    __shared__ float outacc[BC * 2];

    const int tid = threadIdx.x;
    const int w   = tid >> 6;        // wave 0..7: owns hidden [32w, 32w+32)
    const int l   = tid & 63;
    const int lr  = l & 15;          // batch lane (B/D col); A-row lane
    const int lg  = l >> 4;          // k-group 0..3
    const int b0  = blockIdx.x * BC;

    // ---- stage x -> bf16 [t][b] ----
    for (int idx = tid; idx < TT * BC; idx += NTH) {
        int bb = idx >> 8, t = idx & 255;
        xw[t * BC + bb] = f2bf(y_hist[(size_t)(b0 + bb) * TT + t]);
    }
    // ---- stage h0 -> bf16 swizzled LDS buf0 ----
    for (int idx = tid; idx < BC * 128; idx += NTH) {
        int bb = idx >> 7, d = idx & 127;
        const float* hp = &h0[(size_t)(b0 + bb) * HH + 2 * d];
        unsigned val = (unsigned)f2bf(hp[0]) | ((unsigned)f2bf(hp[1]) << 16);
        *(unsigned*)(hb[0] + bb * 512 + ((d * 4) ^ ((bb & 7) << 4))) = val;
    }
    if (tid < BC * 2) outacc[tid] = 0.f;

    // ---- c state: lane owns (batch lr, units 32w+16ch+4lg+r) ----
    float cc[2][4];
#pragma unroll
    for (int ch = 0; ch < 2; ++ch)
#pragma unroll
        for (int r = 0; r < 4; ++r)
            cc[ch][r] = c0[(size_t)(b0 + lr) * HH + 32 * w + 16 * ch + 4 * lg + r];

    // ---- fold A-fragments: a8[tau] = {w_x_row, bias_row} at k=0,1 (lg==0) ----
    short8 a8[8];
#pragma unroll
    for (int tau = 0; tau < 8; ++tau) {
        const int gt = tau & 3, ch = tau >> 2;
        const int row = 256 * gt + 32 * w + 16 * ch + lr;
        short8 a = {0, 0, 0, 0, 0, 0, 0, 0};
        if (lg == 0) {
            a[0] = (short)f2bf(W_ih[row]);
            a[1] = (short)f2bf(b_ih[row] + b_hh[row]);
        }
        a8[tau] = a;
    }

    // ---- W tiles: tau = ch*4 + gt; reg tiles tau 0..5, LDS tiles 6,7 ----
    short8 wfrag[48];
#pragma unroll
    for (int tau = 0; tau < 6; ++tau) {
        const int gt = tau & 3, ch = tau >> 2;
        const int row = 256 * gt + 32 * w + 16 * ch + lr;
#pragma unroll
        for (int s = 0; s < 8; ++s) {
            const float* p = &W_hh[(size_t)row * HH + 8 * lg + 32 * s];
            short8 f;
#pragma unroll
            for (int i = 0; i < 8; ++i) f[i] = (short)f2bf(p[i]);
            wfrag[tau * 8 + s] = f;
        }
    }
#pragma unroll
    for (int i = 0; i < 48; ++i)
        asm volatile("" : "+v"(wfrag[i]));

#pragma unroll
    for (int ti = 0; ti < 2; ++ti) {                 // tau 6,7: ch=1, gt=2+ti
        const int row = 256 * (2 + ti) + 32 * w + 16 + lr;
#pragma unroll
        for (int s = 0; s < 8; ++s) {
            const float* p = &W_hh[(size_t)row * HH + 8 * lg + 32 * s];
            short8 f;
#pragma unroll
            for (int i = 0; i < 8; ++i) f[i] = (short)f2bf(p[i]);
            *(short8*)(WLDS + w * 16384 + ti * 8192 + s * 1024 + l * 16) = f;
        }
    }

    __syncthreads();

    const unsigned sw  = (unsigned)((lr & 7) << 4);
    const unsigned rdb = (unsigned)(lr * 512);
    const unsigned cwb = (unsigned)(64 * w + 8 * lg);   // write col base
    const char* wbase = WLDS + w * 16384 + l * 16;
    const floatx4 zf = {0.f, 0.f, 0.f, 0.f};
    float hv[2][4];

#pragma unroll 1
    for (int t = 0; t < TT; ++t) {
        const char* rb = hb[t & 1];
        char* wbp = hb[(t + 1) & 1];

        // ---- fold as acc-init: acc[tau] = [w_x|bias] @ [x;1] + 0 ----
        unsigned xword = (unsigned)xw[t * BC + lr];
        short8 b8 = {0, 0, 0, 0, 0, 0, 0, 0};
        if (lg == 0) { b8[0] = (short)xword; b8[1] = (short)0x3F80; }
        floatx4 acc[8];
#pragma unroll
        for (int tau = 0; tau < 8; ++tau)
            acc[tau] = __builtin_amdgcn_mfma_f32_16x16x32_bf16(
                           a8[tau], b8, zf, 0, 0, 0);

        // ---- K loop: two half-passes, 12 loads batched then 32 MFMAs ----
#pragma unroll
        for (int half = 0; half < 2; ++half) {
            short8 bfr[4], w6v[4], w7v[4];
#pragma unroll
            for (int si = 0; si < 4; ++si) {
                const int s = half * 4 + si;
                bfr[si] = *(const short8*)(rb + rdb +
                              (((unsigned)(16 * lg + 64 * s)) ^ sw));
                w6v[si] = *(const short8*)(wbase + s * 1024);
                w7v[si] = *(const short8*)(wbase + 8192 + s * 1024);
            }
#pragma unroll
            for (int si = 0; si < 4; ++si) {
                const int s = half * 4 + si;
#pragma unroll
                for (int tau = 0; tau < 6; ++tau)
                    acc[tau] = __builtin_amdgcn_mfma_f32_16x16x32_bf16(
                                   wfrag[tau * 8 + s], bfr[si], acc[tau], 0, 0, 0);
                acc[6] = __builtin_amdgcn_mfma_f32_16x16x32_bf16(
                             w6v[si], bfr[si], acc[6], 0, 0, 0);
                acc[7] = __builtin_amdgcn_mfma_f32_16x16x32_bf16(
                             w7v[si], bfr[si], acc[7], 0, 0, 0);
            }
        }

        // ---- gates -> c,h ----
#pragma unroll
        for (int ch = 0; ch < 2; ++ch) {
#pragma unroll
            for (int r = 0; r < 4; ++r) {
                float iv = sigf(acc[ch * 4 + 0][r]);
                float fv = sigf(acc[ch * 4 + 1][r]);
                float gv = tanh_(acc[ch * 4 + 2][r]);
                float ov = sigf(acc[ch * 4 + 3][r]);
                float c2 = fmaf(fv, cc[ch][r], iv * gv);
                cc[ch][r] = c2;
                hv[ch][r] = ov * tanh_(c2);
            }
            unsigned lo = (unsigned)f2bf(hv[ch][0]) |
                          ((unsigned)f2bf(hv[ch][1]) << 16);
            unsigned hi = (unsigned)f2bf(hv[ch][2]) |
                          ((unsigned)f2bf(hv[ch][3]) << 16);
            uint2 pk; pk.x = lo; pk.y = hi;
            *(uint2*)(wbp + rdb + (((unsigned)(cwb + 32 * ch)) ^ sw)) = pk;
        }

        __syncthreads();
    }

    // ---- epilogue: out = h_T @ W_fc^T + b_fc (block owns its batches) ----
    float p0 = 0.f, p1 = 0.f;
#pragma unroll
    for (int ch = 0; ch < 2; ++ch)
#pragma unroll
        for (int r = 0; r < 4; ++r) {
            const int u = 32 * w + 16 * ch + 4 * lg + r;
            p0 = fmaf(hv[ch][r], W_fc[u],      p0);
            p1 = fmaf(hv[ch][r], W_fc[HH + u], p1);
        }
    p0 += __shfl_xor(p0, 16, 64); p0 += __shfl_xor(p0, 32, 64);
    p1 += __shfl_xor(p1, 16, 64); p1 += __shfl_xor(p1, 32, 64);
    if (lg == 0) {
        atomicAdd(&outacc[lr * 2 + 0], p0);
        atomicAdd(&outacc[lr * 2 + 1], p1);
    }
    __syncthreads();
    if (tid < BC * 2) {
        int bb = tid >> 1, o = tid & 1;
        out[(size_t)(b0 + bb) * 2 + o] = outacc[tid] + b_fc[o];
    }
}

extern "C" void kernel_launch(void* const* d_in, const int* in_sizes, int n_in,
                              void* d_out, int out_size, void* d_ws, size_t ws_size,
                              hipStream_t stream) {
    const float* y_hist = (const float*)d_in[0];
    const float* h0     = (const float*)d_in[1];
    const float* c0     = (const float*)d_in[2];
    const float* W_ih   = (const float*)d_in[3];
    const float* W_hh   = (const float*)d_in[4];
    const float* b_ih   = (const float*)d_in[5];
    const float* b_hh   = (const float*)d_in[6];
    const float* W_fc   = (const float*)d_in[7];
    const float* b_fc   = (const float*)d_in[8];

    lstm_onecu<<<2048 / BC, NTH, 0, stream>>>(
        y_hist, h0, c0, W_ih, W_hh, b_ih, b_hh, W_fc, b_fc, (float*)d_out);
}